// Round 1
// baseline (414.276 us; speedup 1.0000x reference)
//
#include <hip/hip_runtime.h>

#define E_DIM 512
#define U_DIM 64
#define T_DIM 8
#define A_DIM 32
#define NB    10
#define BATCH 8192

__launch_bounds__(256, 4)
__global__ void gatne_kernel(
    const float* __restrict__ node_embeddings,      // [N, 512]
    const float* __restrict__ node_type_embeddings, // [N, 8, 64]
    const float* __restrict__ trans_weights,        // [8, 64, 512]
    const float* __restrict__ trans_weights_s1,     // [8, 64, 32]
    const float* __restrict__ trans_weights_s2,     // [8, 32]
    const int*   __restrict__ train_inputs,         // [B]
    const int*   __restrict__ train_types,          // [B]
    const int*   __restrict__ node_neigh,           // [B, 8, 10]
    float*       __restrict__ out)                  // [B, 512]
{
    const int b   = blockIdx.x;
    const int tid = threadIdx.x;

    __shared__ int   s_neigh[T_DIM * NB];     // 80 ints
    __shared__ float s_nte[T_DIM][U_DIM];     // 2 KB
    __shared__ float s_w1[U_DIM * A_DIM];     // 8 KB
    __shared__ float s_w2[A_DIM];
    __shared__ float s_att[T_DIM];
    __shared__ float s_agg[U_DIM];
    __shared__ float s_red[4];

    const int ni = train_inputs[b];
    const int ty = train_types[b];

    if (tid < T_DIM * NB) s_neigh[tid] = node_neigh[b * (T_DIM * NB) + tid];
    for (int i = tid; i < U_DIM * A_DIM; i += 256)
        s_w1[i] = trans_weights_s1[ty * (U_DIM * A_DIM) + i];
    if (tid < A_DIM) s_w2[tid] = trans_weights_s2[ty * A_DIM + tid];
    __syncthreads();

    // ---- neighbor sum: s_nte[t][u] = sum_n nte[neigh[b,t,n], t, u] ----
    {
        const int u = tid & 63;
        const int g = tid >> 6;               // 0..3, each group does types g and g+4
        #pragma unroll
        for (int k = 0; k < 2; ++k) {
            const int t = g + 4 * k;
            float acc = 0.f;
            #pragma unroll
            for (int n = 0; n < NB; ++n) {
                const int nb = s_neigh[t * NB + n];
                acc += node_type_embeddings[(size_t)nb * (T_DIM * U_DIM) + t * U_DIM + u];
            }
            s_nte[t][u] = acc;
        }
    }
    __syncthreads();

    // ---- attention scores: one thread per (t, a) ----
    {
        const int t = tid >> 5;
        const int a = tid & 31;
        float hsum = 0.f;
        #pragma unroll
        for (int u = 0; u < U_DIM; ++u)
            hsum += s_nte[t][u] * s_w1[u * A_DIM + a];
        float val = tanhf(hsum) * s_w2[a];
        #pragma unroll
        for (int off = 16; off > 0; off >>= 1)
            val += __shfl_down(val, off, 32);
        if (a == 0) s_att[t] = val;           // raw score for now
    }
    __syncthreads();

    // ---- softmax over 8 types (single thread; trivial) ----
    if (tid == 0) {
        float m = s_att[0];
        #pragma unroll
        for (int t = 1; t < T_DIM; ++t) m = fmaxf(m, s_att[t]);
        float e[T_DIM], sum = 0.f;
        #pragma unroll
        for (int t = 0; t < T_DIM; ++t) { e[t] = __expf(s_att[t] - m); sum += e[t]; }
        const float inv = 1.f / sum;
        #pragma unroll
        for (int t = 0; t < T_DIM; ++t) s_att[t] = e[t] * inv;
    }
    __syncthreads();

    // ---- agg[u] = sum_t att[t] * nte[t][u] ----
    if (tid < U_DIM) {
        float acc = 0.f;
        #pragma unroll
        for (int t = 0; t < T_DIM; ++t)
            acc += s_att[t] * s_nte[t][tid];
        s_agg[tid] = acc;
    }
    __syncthreads();

    // ---- out[b, e] = node_embed[e] + sum_u agg[u] * w[ty, u, e]; then L2-normalize ----
    const int e0 = tid * 2;                   // 2 consecutive elements per thread
    const float2 ne = *(const float2*)(node_embeddings + (size_t)ni * E_DIM + e0);
    float v0 = ne.x, v1 = ne.y;
    const float* wbase = trans_weights + (size_t)ty * (U_DIM * E_DIM) + e0;
    #pragma unroll 8
    for (int u = 0; u < U_DIM; ++u) {
        const float a = s_agg[u];
        const float2 wv = *(const float2*)(wbase + (size_t)u * E_DIM);
        v0 = fmaf(a, wv.x, v0);
        v1 = fmaf(a, wv.y, v1);
    }

    float ss = v0 * v0 + v1 * v1;
    #pragma unroll
    for (int off = 32; off > 0; off >>= 1)
        ss += __shfl_down(ss, off, 64);
    if ((tid & 63) == 0) s_red[tid >> 6] = ss;
    __syncthreads();
    const float total = s_red[0] + s_red[1] + s_red[2] + s_red[3];
    const float inv = 1.f / fmaxf(sqrtf(total), 1e-12f);

    float2 o; o.x = v0 * inv; o.y = v1 * inv;
    *(float2*)(out + (size_t)b * E_DIM + e0) = o;
}

extern "C" void kernel_launch(void* const* d_in, const int* in_sizes, int n_in,
                              void* d_out, int out_size, void* d_ws, size_t ws_size,
                              hipStream_t stream) {
    const float* node_embeddings      = (const float*)d_in[0];
    const float* node_type_embeddings = (const float*)d_in[1];
    const float* trans_weights        = (const float*)d_in[2];
    const float* trans_weights_s1     = (const float*)d_in[3];
    const float* trans_weights_s2     = (const float*)d_in[4];
    const int*   train_inputs         = (const int*)d_in[5];
    const int*   train_types          = (const int*)d_in[6];
    const int*   node_neigh           = (const int*)d_in[7];
    float* out = (float*)d_out;

    gatne_kernel<<<BATCH, 256, 0, stream>>>(
        node_embeddings, node_type_embeddings, trans_weights,
        trans_weights_s1, trans_weights_s2,
        train_inputs, train_types, node_neigh, out);
}